// Round 1
// baseline (222.855 us; speedup 1.0000x reference)
//
#include <hip/hip_runtime.h>

// B=2, S=2048, D=1024, H=16, DH=64.
// 3 launches:
//  convert_all : fused W transpose->bf16 and q/k/v fp32->bf16.
//  proj_gemm   : z=3, Outh[w] = Xb @ Wt^T + bias. which==0 pre-scaled by
//                log2e/32 (exp2-domain softmax); which==2 stored transposed
//                [B][H][DH][S] so attn can DMA V without transposing.
//  attn_kernel : flash attention, FIXED-max exp2 softmax. q-tile 256,
//                4 waves x 64 q (qs=4). K tile rows are PERMUTED at staging
//                (LDS row l holds key g(l)=32(st&1)+8*quad+4(st>>1)+r) so the
//                softmax output packs directly into the PV B-fragment in
//                registers -- P never touches LDS. 1 barrier/iter, DMA dbuf.

#define B_ 2
#define S_ 2048
#define D_ 1024
#define H_ 16
#define DH_ 64
#define M_ (B_*S_)   // 4096

#define WT_OFF  ((size_t)3*4194304)            // u16 offset of Wt
#define XB_OFF  (WT_OFF + (size_t)3*1048576)   // u16 offset of Xb slot (q)

typedef __attribute__((ext_vector_type(8))) short short8;
typedef __attribute__((ext_vector_type(4))) float f32x4;
typedef __attribute__((ext_vector_type(4))) unsigned int u32x4;
#define MFMA16(a,b,c) __builtin_amdgcn_mfma_f32_16x16x32_bf16(a,b,c,0,0,0)

typedef __attribute__((address_space(1))) const void* gptr_t;
typedef __attribute__((address_space(3))) void* lptr_t;
static __device__ inline void gload_lds16(const void* g, void* l) {
    __builtin_amdgcn_global_load_lds((gptr_t)g, (lptr_t)l, 16, 0, 0);
}

static __device__ inline unsigned short f2bf(float x) {   // RNE
    union { float f; unsigned u; } v; v.f = x;
    return (unsigned short)((v.u + 0x7fffu + ((v.u >> 16) & 1u)) >> 16);
}
// pack two floats to bf16 pair (round-half-up): 2 adds + 1 v_perm_b32
static __device__ inline unsigned packp(float a, float b) {
    return __builtin_amdgcn_perm(__float_as_uint(b) + 0x8000u,
                                 __float_as_uint(a) + 0x8000u, 0x07060302u);
}

// ---------------------------------------------------------------------------
// Fused conversions. Grid (4096+256, 1, 3).
//   bx <  4096 : X (q/k/v) fp32 -> bf16, 1024 elems/block
//   bx >= 4096 : W fp32 [k][n] -> bf16 Wt [n][k], 64x64 tile via LDS
// ---------------------------------------------------------------------------
__global__ __launch_bounds__(256) void convert_all(
    const float* __restrict__ X0, const float* __restrict__ X1,
    const float* __restrict__ X2,
    const float* __restrict__ Wq, const float* __restrict__ Wk,
    const float* __restrict__ Wv,
    unsigned short* __restrict__ O0, unsigned short* __restrict__ O1,
    unsigned short* __restrict__ O2, unsigned short* __restrict__ WtBase)
{
    __shared__ unsigned short T[64][72];
    const int z = blockIdx.z;
    const int t = threadIdx.x;

    if (blockIdx.x < 4096) {
        const float* X = z==0 ? X0 : (z==1 ? X1 : X2);
        unsigned short* O = z==0 ? O0 : (z==1 ? O1 : O2);
        int idx = blockIdx.x*256 + t;
        float4 xv = *(const float4*)&X[(size_t)idx*4];
        uint2 o;
        o.x = (unsigned)f2bf(xv.x) | ((unsigned)f2bf(xv.y) << 16);
        o.y = (unsigned)f2bf(xv.z) | ((unsigned)f2bf(xv.w) << 16);
        *(uint2*)&O[(size_t)idx*4] = o;
        return;
    }

    const float* W = z==0 ? Wq : (z==1 ? Wk : Wv);
    unsigned short* Out = WtBase + ((size_t)z << 20);
    const int bx2 = blockIdx.x - 4096;
    const int n0 = (bx2 & 15)*64, k0 = (bx2 >> 4)*64;
    const int tk = t >> 4, tn4 = (t & 15)*4;

    #pragma unroll
    for (int i=0;i<4;i++){
        int kk = tk + i*16;
        float4 wv = *(const float4*)&W[(size_t)(k0+kk)*D_ + n0 + tn4];
        T[tn4+0][kk] = f2bf(wv.x);
        T[tn4+1][kk] = f2bf(wv.y);
        T[tn4+2][kk] = f2bf(wv.z);
        T[tn4+3][kk] = f2bf(wv.w);
    }
    __syncthreads();

    const int n = t >> 2, seg = t & 3;
    uint4 a = *(uint4*)&T[n][seg*16];
    uint4 b = *(uint4*)&T[n][seg*16 + 8];
    *(uint4*)&Out[(size_t)(n0+n)*D_ + k0 + seg*16]     = a;
    *(uint4*)&Out[(size_t)(n0+n)*D_ + k0 + seg*16 + 8] = b;
}

// ---------------------------------------------------------------------------
// Projection GEMM, pure-DMA staging, XOR-swizzled LDS. Grid (8,32,3).
// which==0: output scaled by log2e/32.  which==2: output transposed.
// ---------------------------------------------------------------------------
__global__ __launch_bounds__(256) void proj_gemm(
    const unsigned short* __restrict__ A0, const unsigned short* __restrict__ A1,
    const unsigned short* __restrict__ A2, const unsigned short* __restrict__ WtBase,
    const float* __restrict__ b0, const float* __restrict__ b1,
    const float* __restrict__ b2, unsigned short* __restrict__ OutBase)
{
    const int which = blockIdx.z;
    const unsigned short* A  = which==0 ? A0 : (which==1 ? A1 : A2);
    const unsigned short* Bm = WtBase + ((size_t)which << 20);
    const float* bias        = which==0 ? b0 : (which==1 ? b1 : b2);
    unsigned short* Out      = OutBase + ((size_t)which << 22);
    const float oscale = (which==0) ? 0.04508422f : 1.0f;   // log2e/32

    __shared__ __align__(16) unsigned short As[128*64];
    __shared__ __align__(16) unsigned short Bs[128*64];

    const int t    = threadIdx.x;
    const int m0   = blockIdx.y * 128;
    const int n0   = blockIdx.x * 128;
    const int w    = t >> 6;
    const int lane = t & 63;
    const int l15  = lane & 15;
    const int quad = lane >> 4;
    const int wm   = w >> 1, wn = w & 1;

    f32x4 acc[4][4];
    #pragma unroll
    for (int i=0;i<4;i++)
        #pragma unroll
        for (int j=0;j<4;j++) acc[i][j] = (f32x4){0.f,0.f,0.f,0.f};

    float biasv[4];
    #pragma unroll
    for (int nt=0; nt<4; nt++)
        biasv[nt] = bias[n0 + wn*64 + nt*16 + l15];

    int sArow[4], sAkc[4];
    #pragma unroll
    for (int i=0;i<4;i++){
        int s  = (w*4 + i)*64 + lane;
        int r  = s >> 3, cs = s & 7;
        sArow[i] = r;
        sAkc[i]  = ((cs ^ (r & 7)) * 8);
    }

    for (int ks = 0; ks < 16; ++ks) {
        const int kb = ks * 64;
        #pragma unroll
        for (int i=0;i<4;i++){
            int s = (w*4 + i)*64 + lane;
            gload_lds16(A  + (size_t)(m0 + sArow[i])*D_ + kb + sAkc[i], (unsigned short*)As + s*8);
            gload_lds16(Bm + (size_t)(n0 + sArow[i])*D_ + kb + sAkc[i], (unsigned short*)Bs + s*8);
        }
        __syncthreads();

        #pragma unroll
        for (int kh=0; kh<2; kh++){
            short8 aF[4], bF[4];
            #pragma unroll
            for (int mt=0; mt<4; mt++){
                int r  = wm*64 + mt*16 + l15;
                int cs = (kh*4 + quad) ^ (r & 7);
                aF[mt] = *(const short8*)(As + r*64 + cs*8);
            }
            #pragma unroll
            for (int nt=0; nt<4; nt++){
                int r  = wn*64 + nt*16 + l15;
                int cs = (kh*4 + quad) ^ (r & 7);
                bF[nt] = *(const short8*)(Bs + r*64 + cs*8);
            }
            #pragma unroll
            for (int mt=0; mt<4; mt++)
                #pragma unroll
                for (int nt=0; nt<4; nt++)
                    acc[mt][nt] = MFMA16(aF[mt], bF[nt], acc[mt][nt]);
        }
        __syncthreads();
    }

    if (which != 2) {
        #pragma unroll
        for (int nt=0; nt<4; nt++){
            int n  = n0 + wn*64 + nt*16 + l15;
            int hh = n >> 6, dh = n & 63;
            #pragma unroll
            for (int mt=0; mt<4; mt++){
                #pragma unroll
                for (int r=0; r<4; r++){
                    int m  = m0 + wm*64 + mt*16 + quad*4 + r;
                    int bb = m >> 11, ss = m & (S_-1);
                    float v = (acc[mt][nt][r] + biasv[nt]) * oscale;
                    Out[((size_t)((bb*H_ + hh)*S_ + ss))*DH_ + dh] = f2bf(v);
                }
            }
        }
    } else {
        #pragma unroll
        for (int nt=0; nt<4; nt++){
            int n  = n0 + wn*64 + nt*16 + l15;
            int hh = n >> 6, dh = n & 63;
            #pragma unroll
            for (int mt=0; mt<4; mt++){
                int m  = m0 + wm*64 + mt*16 + quad*4;
                int bb = m >> 11, ss = m & (S_-1);
                uint2 pk;
                pk.x = packp(acc[mt][nt][0] + biasv[nt], acc[mt][nt][1] + biasv[nt]);
                pk.y = packp(acc[mt][nt][2] + biasv[nt], acc[mt][nt][3] + biasv[nt]);
                *(uint2*)&Out[((size_t)((bb*H_ + hh)*DH_ + dh))*S_ + ss] = pk;
            }
        }
    }
}

// ---------------------------------------------------------------------------
// Flash attention, fixed-max exp2 softmax, in-register P.
// Block = 256 q of one (b,h); 4 waves x 64 q (qs=4). 64-key tiles, DMA dbuf,
// 1 barrier/iter. Grid (8,16,2) = 256 blocks = 1/CU; XCD-swizzled so the 8
// q-blocks of a (b,h) share an XCD L2 (K/V = 512KB << 4MB).
//
// Key-row permutation: LDS K row l holds global key
//   g(l) = 32*(st&1) + 8*quad + 4*(st>>1) + r   (l = st*16+quad*4+r)
// so QK^T output sc[st][r] (lane quad) is the score of key 32(st&1)+8q+4(st>>1)+r,
// and {st0,st2} / {st1,st3} pack directly into pf0/pf1 (PV B-frag, k=quad*8+j).
// V^T is stored by TRUE key, matching the B-frag k index.
// ---------------------------------------------------------------------------
__global__ __launch_bounds__(256, 1) void attn_kernel(
    const unsigned short* __restrict__ ws, const int* __restrict__ mask,
    float* __restrict__ out)
{
    const unsigned short* Qh = ws;                      // [B][H][S][64], exp2-scaled
    const unsigned short* Kh = ws + (size_t)M_*D_;      // [B][H][S][64]
    const unsigned short* Vg = ws + 2*(size_t)M_*D_;    // [B][H][64][S]

    // XCD swizzle: all 8 q-tiles of one (b,h) land on the same XCD.
    const int lin = blockIdx.x + (blockIdx.y << 3) + (blockIdx.z << 7);
    const int Wn  = (lin & 7)*32 + (lin >> 3);
    const int qt = Wn & 7;
    const int h  = (Wn >> 3) & 15;
    const int bb = Wn >> 7;

    const size_t base = ((size_t)(bb*H_ + h)) * S_ * DH_;
    const int q0 = qt * 256;

    __shared__ __align__(16) unsigned char smem[34816];
    unsigned short* KsB = (unsigned short*)smem;            // [2][64][64] key-permuted
    unsigned short* VtB = (unsigned short*)(smem + 16384);  // [2][64][64] true-key order
    float*          MsB = (float*)(smem + 32768);           // [2][64]
    float*          Ob  = (float*)smem;                     // [128][68] alias (epilogue)

    const int t    = threadIdx.x;
    const int w    = t >> 6;
    const int lane = t & 63;
    const int l15  = lane & 15;
    const int quad = lane >> 4;

    short8 qf[4][2];
    #pragma unroll
    for (int qs=0; qs<4; qs++){
        const unsigned short* qp = Qh + base + (size_t)(q0 + w*64 + qs*16 + l15)*DH_ + quad*8;
        qf[qs][0] = *(const short8*)(qp);
        qf[qs][1] = *(const short8*)(qp + 32);
    }

    f32x4 accO[4][4];
    #pragma unroll
    for (int qs=0; qs<4; qs++)
        #pragma unroll
        for (int i=0;i<4;i++) accO[qs][i] = (f32x4){0.f,0.f,0.f,0.f};
    float l_run[4] = {0.f, 0.f, 0.f, 0.f};

    // staging slots: 512 slots of 16B; K source row permuted by g(l)
    int rr[2], cc[2], ssl[2], gK[2];
    #pragma unroll
    for (int i=0;i<2;i++){
        int s = (w*2 + i)*64 + lane;
        int r = s >> 3, cs = s & 7;
        ssl[i] = s;
        rr[i]  = r;
        cc[i]  = (cs ^ (r & 7)) * 8;
        gK[i]  = ((r >> 4) & 1)*32 + ((r >> 2) & 3)*8 + (r >> 5)*4 + (r & 3);
    }

    #define ISSUE(k0v, p) do {                                                 \
        _Pragma("unroll")                                                      \
        for (int i=0;i<2;i++){                                                 \
            gload_lds16(Kh + base + (size_t)((k0v) + gK[i])*DH_ + cc[i],       \
                        KsB + (p)*4096 + ssl[i]*8);                            \
            gload_lds16(Vg + base + (size_t)rr[i]*S_ + (k0v) + cc[i],          \
                        VtB + (p)*4096 + ssl[i]*8);                            \
        }                                                                      \
    } while(0)

    ISSUE(0, 0);
    if (t < 64) MsB[t] = mask[bb*S_ + t] ? 0.f : -1e9f;
    __syncthreads();

    for (int it = 0; it < 32; ++it){
        const int p = it & 1;
        int mR = 0;
        if (it < 31){
            ISSUE((it+1)*64, 1-p);
            if (t < 64) mR = mask[bb*S_ + (it+1)*64 + t];
        }
        const unsigned short* Ks  = KsB + p*4096;
        const unsigned short* Vts = VtB + p*4096;
        const float* Ms = MsB + p*64;

        // mask in permuted-key order: key(st,quad,r) = 32(st&1)+4(st>>1)+8quad+r
        f32x4 msv[4];
        #pragma unroll
        for (int st=0; st<4; st++)
            msv[st] = *(const f32x4*)&Ms[(st&1)*32 + (st>>1)*4 + quad*8];

        // K/V fragments: loaded ONCE per iter, shared by all 4 qs chains
        short8 ka[4], kb[4];
        #pragma unroll
        for (int st=0; st<4; st++){
            int row = st*16 + l15;
            const unsigned short* kr = Ks + row*64;
            ka[st] = *(const short8*)(kr + ((quad    ) ^ (row & 7))*8);
            kb[st] = *(const short8*)(kr + ((quad + 4) ^ (row & 7))*8);
        }
        short8 vf[4][2];
        #pragma unroll
        for (int mt=0; mt<4; mt++){
            int row = mt*16 + l15;
            const unsigned short* vr = Vts + row*64;
            vf[mt][0] = *(const short8*)(vr + ((quad    ) ^ (row & 7))*8);
            vf[mt][1] = *(const short8*)(vr + ((quad + 4) ^ (row & 7))*8);
        }

        #pragma unroll
        for (int qs=0; qs<4; qs++){
            // ---- scores: S^T = K·Q^T (exp2-domain, pre-scaled Q) ----
            f32x4 sc[4];
            #pragma unroll
            for (int st=0; st<4; st++){
                f32x4 a = (f32x4){0.f,0.f,0.f,0.f};
                a = MFMA16(ka[st], qf[qs][0], a);
                a = MFMA16(kb[st], qf[qs][1], a);
                sc[st] = a;
            }
            // ---- fixed-max softmax, packed straight into PV B-frag ----
            float pv[4][4]; float lacc = 0.f;
            #pragma unroll
            for (int st=0; st<4; st++)
                #pragma unroll
                for (int rj=0; rj<4; rj++){
                    pv[st][rj] = __builtin_amdgcn_exp2f(sc[st][rj] + msv[st][rj]);
                    lacc += pv[st][rj];
                }
            l_run[qs] += lacc;
            u32x4 u0 = { packp(pv[0][0],pv[0][1]), packp(pv[0][2],pv[0][3]),
                         packp(pv[2][0],pv[2][1]), packp(pv[2][2],pv[2][3]) };
            u32x4 u1 = { packp(pv[1][0],pv[1][1]), packp(pv[1][2],pv[1][3]),
                         packp(pv[3][0],pv[3][1]), packp(pv[3][2],pv[3][3]) };
            short8 pf0 = __builtin_bit_cast(short8, u0);
            short8 pf1 = __builtin_bit_cast(short8, u1);
            // ---- PV: O^T += V^T · P^T (P entirely in registers) ----
            #pragma unroll
            for (int mt=0; mt<4; mt++){
                accO[qs][mt] = MFMA16(vf[mt][0], pf0, accO[qs][mt]);
                accO[qs][mt] = MFMA16(vf[mt][1], pf1, accO[qs][mt]);
            }
        }

        if (it < 31 && t < 64) MsB[(1-p)*64 + t] = mR ? 0.f : -1e9f;
        __syncthreads();
    }

    // ---- epilogue: reduce l across quads once, normalize, 2-chunk transpose ----
    float invl[4];
    #pragma unroll
    for (int qs=0; qs<4; qs++){
        float l = l_run[qs];
        l += __shfl_xor(l, 16);
        l += __shfl_xor(l, 32);
        invl[qs] = 1.0f / fmaxf(l, 1e-30f);
    }
    #pragma unroll
    for (int c=0; c<2; c++){
        if ((w >> 1) == c){
            #pragma unroll
            for (int qs=0; qs<4; qs++)
                #pragma unroll
                for (int mt=0; mt<4; mt++)
                    #pragma unroll
                    for (int rj=0; rj<4; rj++)
                        Ob[((w&1)*64 + qs*16 + l15)*68 + mt*16 + quad*4 + rj]
                            = accO[qs][mt][rj]*invl[qs];
        }
        __syncthreads();
        #pragma unroll
        for (int i=0;i<8;i++){
            int f  = (i*256 + t)*4;
            int qq = f >> 6, dh = f & 63;
            float4 o = *(float4*)&Ob[qq*68 + dh];
            *(float4*)&out[((size_t)(bb*S_ + q0 + c*128 + qq))*D_ + h*DH_ + dh] = o;
        }
        __syncthreads();
    }
    #undef ISSUE
}

extern "C" void kernel_launch(void* const* d_in, const int* in_sizes, int n_in,
                              void* d_out, int out_size, void* d_ws, size_t ws_size,
                              hipStream_t stream) {
    const float* q    = (const float*)d_in[0];
    const float* k    = (const float*)d_in[1];
    const float* v    = (const float*)d_in[2];
    const int*   mask = (const int*)d_in[3];
    const float* Wq   = (const float*)d_in[4];
    const float* b0   = (const float*)d_in[5];
    const float* Wk   = (const float*)d_in[6];
    const float* b1   = (const float*)d_in[7];
    const float* Wv   = (const float*)d_in[8];
    const float* b2   = (const float*)d_in[9];
    float* out = (float*)d_out;
    unsigned short* ws = (unsigned short*)d_ws;   // 39.85 MB used

    // Xb slots: q -> ws; k,v -> d_out (scratch until attn overwrites it last)
    unsigned short* xq = ws + XB_OFF;
    unsigned short* xk = (unsigned short*)d_out;
    unsigned short* xv = (unsigned short*)d_out + 4194304;

    convert_all<<<dim3(4352,1,3), 256, 0, stream>>>(q, k, v, Wq, Wk, Wv,
                                                    xq, xk, xv, ws + WT_OFF);
    proj_gemm<<<dim3(8,32,3), 256, 0, stream>>>(xq, xk, xv, ws + WT_OFF,
                                                b0, b1, b2, ws);
    attn_kernel<<<dim3(8,16,2), 256, 0, stream>>>(ws, mask, out);
}

// Round 2
// 206.286 us; speedup vs baseline: 1.0803x; 1.0803x over previous
//
#include <hip/hip_runtime.h>

// B=2, S=2048, D=1024, H=16, DH=64.
// 3 launches:
//  convert_all : fused W transpose->bf16 and q/k/v fp32->bf16.
//  proj_gemm   : z=3, Outh[w] = Xb @ Wt^T + bias. which==0 pre-scaled by
//                log2e/32 (exp2-domain softmax); which==2 stored transposed
//                [B][H][DH][S] so attn can DMA V without transposing.
//  attn_kernel : flash attention, FIXED-max exp2 softmax. q-tile 128,
//                4 waves x 32 q (qs=2), grid 512 = 2 blocks/CU (R1 lesson:
//                1 wave/SIMD is latency-bound; R0 proved 2 blocks/CU
//                saturates the LDS pipe). K tile rows PERMUTED at staging so
//                softmax output packs directly into the PV B-fragment in
//                registers -- P never touches LDS (R1 win, kept).

#define B_ 2
#define S_ 2048
#define D_ 1024
#define H_ 16
#define DH_ 64
#define M_ (B_*S_)   // 4096

#define WT_OFF  ((size_t)3*4194304)            // u16 offset of Wt
#define XB_OFF  (WT_OFF + (size_t)3*1048576)   // u16 offset of Xb slot (q)

typedef __attribute__((ext_vector_type(8))) short short8;
typedef __attribute__((ext_vector_type(4))) float f32x4;
typedef __attribute__((ext_vector_type(4))) unsigned int u32x4;
#define MFMA16(a,b,c) __builtin_amdgcn_mfma_f32_16x16x32_bf16(a,b,c,0,0,0)

typedef __attribute__((address_space(1))) const void* gptr_t;
typedef __attribute__((address_space(3))) void* lptr_t;
static __device__ inline void gload_lds16(const void* g, void* l) {
    __builtin_amdgcn_global_load_lds((gptr_t)g, (lptr_t)l, 16, 0, 0);
}

static __device__ inline unsigned short f2bf(float x) {   // RNE
    union { float f; unsigned u; } v; v.f = x;
    return (unsigned short)((v.u + 0x7fffu + ((v.u >> 16) & 1u)) >> 16);
}
// pack two floats to bf16 pair (round-half-up): 2 adds + 1 v_perm_b32
static __device__ inline unsigned packp(float a, float b) {
    return __builtin_amdgcn_perm(__float_as_uint(b) + 0x8000u,
                                 __float_as_uint(a) + 0x8000u, 0x07060302u);
}

// ---------------------------------------------------------------------------
// Fused conversions. Grid (4096+256, 1, 3).
//   bx <  4096 : X (q/k/v) fp32 -> bf16, 1024 elems/block
//   bx >= 4096 : W fp32 [k][n] -> bf16 Wt [n][k], 64x64 tile via LDS
// ---------------------------------------------------------------------------
__global__ __launch_bounds__(256) void convert_all(
    const float* __restrict__ X0, const float* __restrict__ X1,
    const float* __restrict__ X2,
    const float* __restrict__ Wq, const float* __restrict__ Wk,
    const float* __restrict__ Wv,
    unsigned short* __restrict__ O0, unsigned short* __restrict__ O1,
    unsigned short* __restrict__ O2, unsigned short* __restrict__ WtBase)
{
    __shared__ unsigned short T[64][72];
    const int z = blockIdx.z;
    const int t = threadIdx.x;

    if (blockIdx.x < 4096) {
        const float* X = z==0 ? X0 : (z==1 ? X1 : X2);
        unsigned short* O = z==0 ? O0 : (z==1 ? O1 : O2);
        int idx = blockIdx.x*256 + t;
        float4 xv = *(const float4*)&X[(size_t)idx*4];
        uint2 o;
        o.x = (unsigned)f2bf(xv.x) | ((unsigned)f2bf(xv.y) << 16);
        o.y = (unsigned)f2bf(xv.z) | ((unsigned)f2bf(xv.w) << 16);
        *(uint2*)&O[(size_t)idx*4] = o;
        return;
    }

    const float* W = z==0 ? Wq : (z==1 ? Wk : Wv);
    unsigned short* Out = WtBase + ((size_t)z << 20);
    const int bx2 = blockIdx.x - 4096;
    const int n0 = (bx2 & 15)*64, k0 = (bx2 >> 4)*64;
    const int tk = t >> 4, tn4 = (t & 15)*4;

    #pragma unroll
    for (int i=0;i<4;i++){
        int kk = tk + i*16;
        float4 wv = *(const float4*)&W[(size_t)(k0+kk)*D_ + n0 + tn4];
        T[tn4+0][kk] = f2bf(wv.x);
        T[tn4+1][kk] = f2bf(wv.y);
        T[tn4+2][kk] = f2bf(wv.z);
        T[tn4+3][kk] = f2bf(wv.w);
    }
    __syncthreads();

    const int n = t >> 2, seg = t & 3;
    uint4 a = *(uint4*)&T[n][seg*16];
    uint4 b = *(uint4*)&T[n][seg*16 + 8];
    *(uint4*)&Out[(size_t)(n0+n)*D_ + k0 + seg*16]     = a;
    *(uint4*)&Out[(size_t)(n0+n)*D_ + k0 + seg*16 + 8] = b;
}

// ---------------------------------------------------------------------------
// Projection GEMM, pure-DMA staging, XOR-swizzled LDS. Grid (8,32,3).
// which==0: output scaled by log2e/32.  which==2: output transposed.
// ---------------------------------------------------------------------------
__global__ __launch_bounds__(256) void proj_gemm(
    const unsigned short* __restrict__ A0, const unsigned short* __restrict__ A1,
    const unsigned short* __restrict__ A2, const unsigned short* __restrict__ WtBase,
    const float* __restrict__ b0, const float* __restrict__ b1,
    const float* __restrict__ b2, unsigned short* __restrict__ OutBase)
{
    const int which = blockIdx.z;
    const unsigned short* A  = which==0 ? A0 : (which==1 ? A1 : A2);
    const unsigned short* Bm = WtBase + ((size_t)which << 20);
    const float* bias        = which==0 ? b0 : (which==1 ? b1 : b2);
    unsigned short* Out      = OutBase + ((size_t)which << 22);
    const float oscale = (which==0) ? 0.04508422f : 1.0f;   // log2e/32

    __shared__ __align__(16) unsigned short As[128*64];
    __shared__ __align__(16) unsigned short Bs[128*64];

    const int t    = threadIdx.x;
    const int m0   = blockIdx.y * 128;
    const int n0   = blockIdx.x * 128;
    const int w    = t >> 6;
    const int lane = t & 63;
    const int l15  = lane & 15;
    const int quad = lane >> 4;
    const int wm   = w >> 1, wn = w & 1;

    f32x4 acc[4][4];
    #pragma unroll
    for (int i=0;i<4;i++)
        #pragma unroll
        for (int j=0;j<4;j++) acc[i][j] = (f32x4){0.f,0.f,0.f,0.f};

    float biasv[4];
    #pragma unroll
    for (int nt=0; nt<4; nt++)
        biasv[nt] = bias[n0 + wn*64 + nt*16 + l15];

    int sArow[4], sAkc[4];
    #pragma unroll
    for (int i=0;i<4;i++){
        int s  = (w*4 + i)*64 + lane;
        int r  = s >> 3, cs = s & 7;
        sArow[i] = r;
        sAkc[i]  = ((cs ^ (r & 7)) * 8);
    }

    for (int ks = 0; ks < 16; ++ks) {
        const int kb = ks * 64;
        #pragma unroll
        for (int i=0;i<4;i++){
            int s = (w*4 + i)*64 + lane;
            gload_lds16(A  + (size_t)(m0 + sArow[i])*D_ + kb + sAkc[i], (unsigned short*)As + s*8);
            gload_lds16(Bm + (size_t)(n0 + sArow[i])*D_ + kb + sAkc[i], (unsigned short*)Bs + s*8);
        }
        __syncthreads();

        #pragma unroll
        for (int kh=0; kh<2; kh++){
            short8 aF[4], bF[4];
            #pragma unroll
            for (int mt=0; mt<4; mt++){
                int r  = wm*64 + mt*16 + l15;
                int cs = (kh*4 + quad) ^ (r & 7);
                aF[mt] = *(const short8*)(As + r*64 + cs*8);
            }
            #pragma unroll
            for (int nt=0; nt<4; nt++){
                int r  = wn*64 + nt*16 + l15;
                int cs = (kh*4 + quad) ^ (r & 7);
                bF[nt] = *(const short8*)(Bs + r*64 + cs*8);
            }
            #pragma unroll
            for (int mt=0; mt<4; mt++)
                #pragma unroll
                for (int nt=0; nt<4; nt++)
                    acc[mt][nt] = MFMA16(aF[mt], bF[nt], acc[mt][nt]);
        }
        __syncthreads();
    }

    if (which != 2) {
        #pragma unroll
        for (int nt=0; nt<4; nt++){
            int n  = n0 + wn*64 + nt*16 + l15;
            int hh = n >> 6, dh = n & 63;
            #pragma unroll
            for (int mt=0; mt<4; mt++){
                #pragma unroll
                for (int r=0; r<4; r++){
                    int m  = m0 + wm*64 + mt*16 + quad*4 + r;
                    int bb = m >> 11, ss = m & (S_-1);
                    float v = (acc[mt][nt][r] + biasv[nt]) * oscale;
                    Out[((size_t)((bb*H_ + hh)*S_ + ss))*DH_ + dh] = f2bf(v);
                }
            }
        }
    } else {
        #pragma unroll
        for (int nt=0; nt<4; nt++){
            int n  = n0 + wn*64 + nt*16 + l15;
            int hh = n >> 6, dh = n & 63;
            #pragma unroll
            for (int mt=0; mt<4; mt++){
                int m  = m0 + wm*64 + mt*16 + quad*4;
                int bb = m >> 11, ss = m & (S_-1);
                uint2 pk;
                pk.x = packp(acc[mt][nt][0] + biasv[nt], acc[mt][nt][1] + biasv[nt]);
                pk.y = packp(acc[mt][nt][2] + biasv[nt], acc[mt][nt][3] + biasv[nt]);
                *(uint2*)&Out[((size_t)((bb*H_ + hh)*DH_ + dh))*S_ + ss] = pk;
            }
        }
    }
}

// ---------------------------------------------------------------------------
// Flash attention, fixed-max exp2 softmax, in-register P.
// Block = 128 q of one (b,h); 4 waves x 32 q (qs=2). 64-key tiles, DMA dbuf,
// 1 barrier/iter. Grid (16,16,2) = 512 blocks = 2/CU (2 waves/SIMD: enough
// TLP to hide ds_read latency + the barrier's DMA drain -- R1 lesson).
// XCD-swizzled: each XCD serves 4 heads (2 MB K/V < 4 MB L2).
//
// Key-row permutation: LDS K row l holds global key
//   g(l) = 32*(st&1) + 8*quad + 4*(st>>1) + r   (l = st*16+quad*4+r)
// so QK^T output sc[st][r] (lane quad) is the score of key 32(st&1)+8q+4(st>>1)+r,
// and {st0,st2} / {st1,st3} pack directly into pf0/pf1 (PV B-frag, k=quad*8+j).
// V^T is stored by TRUE key, matching the B-frag k index.
// ---------------------------------------------------------------------------
__global__ __launch_bounds__(256, 2) void attn_kernel(
    const unsigned short* __restrict__ ws, const int* __restrict__ mask,
    float* __restrict__ out)
{
    const unsigned short* Qh = ws;                      // [B][H][S][64], exp2-scaled
    const unsigned short* Kh = ws + (size_t)M_*D_;      // [B][H][S][64]
    const unsigned short* Vg = ws + 2*(size_t)M_*D_;    // [B][H][64][S]

    // XCD swizzle: XCD x gets 64 consecutive Wn values = all 16 q-tiles of
    // 4 heads -> 2 MB K/V working set per XCD L2.
    const int lin = blockIdx.x + (blockIdx.y << 4) + (blockIdx.z << 8);
    const int Wn  = (lin & 7)*64 + (lin >> 3);
    const int qt = Wn & 15;
    const int h  = (Wn >> 4) & 15;
    const int bb = Wn >> 8;

    const size_t base = ((size_t)(bb*H_ + h)) * S_ * DH_;
    const int q0 = qt * 128;

    __shared__ __align__(16) unsigned char smem[34816];
    unsigned short* KsB = (unsigned short*)smem;            // [2][64][64] key-permuted
    unsigned short* VtB = (unsigned short*)(smem + 16384);  // [2][64][64] true-key order
    float*          MsB = (float*)(smem + 32768);           // [2][64]
    float*          Ob  = (float*)smem;                     // [128][68] alias (epilogue)

    const int t    = threadIdx.x;
    const int w    = t >> 6;
    const int lane = t & 63;
    const int l15  = lane & 15;
    const int quad = lane >> 4;

    short8 qf[2][2];
    #pragma unroll
    for (int qs=0; qs<2; qs++){
        const unsigned short* qp = Qh + base + (size_t)(q0 + w*32 + qs*16 + l15)*DH_ + quad*8;
        qf[qs][0] = *(const short8*)(qp);
        qf[qs][1] = *(const short8*)(qp + 32);
    }

    f32x4 accO[2][4];
    #pragma unroll
    for (int qs=0; qs<2; qs++)
        #pragma unroll
        for (int i=0;i<4;i++) accO[qs][i] = (f32x4){0.f,0.f,0.f,0.f};
    float l_run[2] = {0.f, 0.f};

    // staging slots: 512 slots of 16B; K source row permuted by g(l)
    int rr[2], cc[2], ssl[2], gK[2];
    #pragma unroll
    for (int i=0;i<2;i++){
        int s = (w*2 + i)*64 + lane;
        int r = s >> 3, cs = s & 7;
        ssl[i] = s;
        rr[i]  = r;
        cc[i]  = (cs ^ (r & 7)) * 8;
        gK[i]  = ((r >> 4) & 1)*32 + ((r >> 2) & 3)*8 + (r >> 5)*4 + (r & 3);
    }

    #define ISSUE(k0v, p) do {                                                 \
        _Pragma("unroll")                                                      \
        for (int i=0;i<2;i++){                                                 \
            gload_lds16(Kh + base + (size_t)((k0v) + gK[i])*DH_ + cc[i],       \
                        KsB + (p)*4096 + ssl[i]*8);                            \
            gload_lds16(Vg + base + (size_t)rr[i]*S_ + (k0v) + cc[i],          \
                        VtB + (p)*4096 + ssl[i]*8);                            \
        }                                                                      \
    } while(0)

    ISSUE(0, 0);
    if (t < 64) MsB[t] = mask[bb*S_ + t] ? 0.f : -1e9f;
    __syncthreads();

    for (int it = 0; it < 32; ++it){
        const int p = it & 1;
        int mR = 0;
        if (it < 31){
            ISSUE((it+1)*64, 1-p);
            if (t < 64) mR = mask[bb*S_ + (it+1)*64 + t];
        }
        const unsigned short* Ks  = KsB + p*4096;
        const unsigned short* Vts = VtB + p*4096;
        const float* Ms = MsB + p*64;

        // mask in permuted-key order: key(st,quad,r) = 32(st&1)+4(st>>1)+8quad+r
        f32x4 msv[4];
        #pragma unroll
        for (int st=0; st<4; st++)
            msv[st] = *(const f32x4*)&Ms[(st&1)*32 + (st>>1)*4 + quad*8];

        // K/V fragments: loaded ONCE per iter, shared by both qs chains
        short8 ka[4], kb[4];
        #pragma unroll
        for (int st=0; st<4; st++){
            int row = st*16 + l15;
            const unsigned short* kr = Ks + row*64;
            ka[st] = *(const short8*)(kr + ((quad    ) ^ (row & 7))*8);
            kb[st] = *(const short8*)(kr + ((quad + 4) ^ (row & 7))*8);
        }
        short8 vf[4][2];
        #pragma unroll
        for (int mt=0; mt<4; mt++){
            int row = mt*16 + l15;
            const unsigned short* vr = Vts + row*64;
            vf[mt][0] = *(const short8*)(vr + ((quad    ) ^ (row & 7))*8);
            vf[mt][1] = *(const short8*)(vr + ((quad + 4) ^ (row & 7))*8);
        }

        #pragma unroll
        for (int qs=0; qs<2; qs++){
            // ---- scores: S^T = K·Q^T (exp2-domain, pre-scaled Q) ----
            f32x4 sc[4];
            #pragma unroll
            for (int st=0; st<4; st++){
                f32x4 a = (f32x4){0.f,0.f,0.f,0.f};
                a = MFMA16(ka[st], qf[qs][0], a);
                a = MFMA16(kb[st], qf[qs][1], a);
                sc[st] = a;
            }
            // ---- fixed-max softmax, packed straight into PV B-frag ----
            float pv[4][4]; float lacc = 0.f;
            #pragma unroll
            for (int st=0; st<4; st++)
                #pragma unroll
                for (int rj=0; rj<4; rj++){
                    pv[st][rj] = __builtin_amdgcn_exp2f(sc[st][rj] + msv[st][rj]);
                    lacc += pv[st][rj];
                }
            l_run[qs] += lacc;
            u32x4 u0 = { packp(pv[0][0],pv[0][1]), packp(pv[0][2],pv[0][3]),
                         packp(pv[2][0],pv[2][1]), packp(pv[2][2],pv[2][3]) };
            u32x4 u1 = { packp(pv[1][0],pv[1][1]), packp(pv[1][2],pv[1][3]),
                         packp(pv[3][0],pv[3][1]), packp(pv[3][2],pv[3][3]) };
            short8 pf0 = __builtin_bit_cast(short8, u0);
            short8 pf1 = __builtin_bit_cast(short8, u1);
            // ---- PV: O^T += V^T · P^T (P entirely in registers) ----
            #pragma unroll
            for (int mt=0; mt<4; mt++){
                accO[qs][mt] = MFMA16(vf[mt][0], pf0, accO[qs][mt]);
                accO[qs][mt] = MFMA16(vf[mt][1], pf1, accO[qs][mt]);
            }
        }

        if (it < 31 && t < 64) MsB[(1-p)*64 + t] = mR ? 0.f : -1e9f;
        __syncthreads();
    }

    // ---- epilogue: reduce l across quads ONCE, normalize, transpose, store ----
    #pragma unroll
    for (int qs=0; qs<2; qs++){
        float l = l_run[qs];
        l += __shfl_xor(l, 16);
        l += __shfl_xor(l, 32);
        float invl = 1.0f / fmaxf(l, 1e-30f);
        #pragma unroll
        for (int mt=0; mt<4; mt++)
            #pragma unroll
            for (int r=0; r<4; r++)
                Ob[(w*32 + qs*16 + l15)*68 + mt*16 + quad*4 + r] = accO[qs][mt][r]*invl;
    }
    __syncthreads();

    #pragma unroll
    for (int i=0;i<8;i++){
        int f  = (i*256 + t)*4;
        int qq = f >> 6, dh = f & 63;
        float4 o = *(float4*)&Ob[qq*68 + dh];
        *(float4*)&out[((size_t)(bb*S_ + q0 + qq))*D_ + h*DH_ + dh] = o;
    }
    #undef ISSUE
}

extern "C" void kernel_launch(void* const* d_in, const int* in_sizes, int n_in,
                              void* d_out, int out_size, void* d_ws, size_t ws_size,
                              hipStream_t stream) {
    const float* q    = (const float*)d_in[0];
    const float* k    = (const float*)d_in[1];
    const float* v    = (const float*)d_in[2];
    const int*   mask = (const int*)d_in[3];
    const float* Wq   = (const float*)d_in[4];
    const float* b0   = (const float*)d_in[5];
    const float* Wk   = (const float*)d_in[6];
    const float* b1   = (const float*)d_in[7];
    const float* Wv   = (const float*)d_in[8];
    const float* b2   = (const float*)d_in[9];
    float* out = (float*)d_out;
    unsigned short* ws = (unsigned short*)d_ws;   // 39.85 MB used

    // Xb slots: q -> ws; k,v -> d_out (scratch until attn overwrites it last)
    unsigned short* xq = ws + XB_OFF;
    unsigned short* xk = (unsigned short*)d_out;
    unsigned short* xv = (unsigned short*)d_out + 4194304;

    convert_all<<<dim3(4352,1,3), 256, 0, stream>>>(q, k, v, Wq, Wk, Wv,
                                                    xq, xk, xv, ws + WT_OFF);
    proj_gemm<<<dim3(8,32,3), 256, 0, stream>>>(xq, xk, xv, ws + WT_OFF,
                                                b0, b1, b2, ws);
    attn_kernel<<<dim3(16,16,2), 256, 0, stream>>>(ws, mask, out);
}

// Round 3
// 202.163 us; speedup vs baseline: 1.1024x; 1.0204x over previous
//
#include <hip/hip_runtime.h>

// B=2, S=2048, D=1024, H=16, DH=64.
// 3 launches:
//  convert_all : fused W transpose->bf16 and q/k/v fp32->bf16.
//  proj_gemm   : z=3, Outh[w] = Xb @ Wt^T + bias. which==0 pre-scaled by
//                log2e/32 (exp2-domain softmax); which==2 stored transposed
//                [B][H][DH][S] so attn can DMA V without transposing.
//  attn_kernel : flash attention, FIXED-max exp2 softmax, in-register P.
//                R3: 128-key iters (2 sub-tiles per barrier -> 16 barriers),
//                static LDS mask-bias table folded into QK MFMA acc-init,
//                vector (tree) l accumulation, setprio around MFMA clusters.

#define B_ 2
#define S_ 2048
#define D_ 1024
#define H_ 16
#define DH_ 64
#define M_ (B_*S_)   // 4096

#define WT_OFF  ((size_t)3*4194304)            // u16 offset of Wt
#define XB_OFF  (WT_OFF + (size_t)3*1048576)   // u16 offset of Xb slot (q)

typedef __attribute__((ext_vector_type(8))) short short8;
typedef __attribute__((ext_vector_type(4))) float f32x4;
typedef __attribute__((ext_vector_type(4))) unsigned int u32x4;
#define MFMA16(a,b,c) __builtin_amdgcn_mfma_f32_16x16x32_bf16(a,b,c,0,0,0)

typedef __attribute__((address_space(1))) const void* gptr_t;
typedef __attribute__((address_space(3))) void* lptr_t;
static __device__ inline void gload_lds16(const void* g, void* l) {
    __builtin_amdgcn_global_load_lds((gptr_t)g, (lptr_t)l, 16, 0, 0);
}

static __device__ inline unsigned short f2bf(float x) {   // RNE
    union { float f; unsigned u; } v; v.f = x;
    return (unsigned short)((v.u + 0x7fffu + ((v.u >> 16) & 1u)) >> 16);
}
// pack two floats to bf16 pair (round-half-up): 2 adds + 1 v_perm_b32
static __device__ inline unsigned packp(float a, float b) {
    return __builtin_amdgcn_perm(__float_as_uint(b) + 0x8000u,
                                 __float_as_uint(a) + 0x8000u, 0x07060302u);
}

// ---------------------------------------------------------------------------
// Fused conversions. Grid (4096+256, 1, 3).
//   bx <  4096 : X (q/k/v) fp32 -> bf16, 1024 elems/block
//   bx >= 4096 : W fp32 [k][n] -> bf16 Wt [n][k], 64x64 tile via LDS
// ---------------------------------------------------------------------------
__global__ __launch_bounds__(256) void convert_all(
    const float* __restrict__ X0, const float* __restrict__ X1,
    const float* __restrict__ X2,
    const float* __restrict__ Wq, const float* __restrict__ Wk,
    const float* __restrict__ Wv,
    unsigned short* __restrict__ O0, unsigned short* __restrict__ O1,
    unsigned short* __restrict__ O2, unsigned short* __restrict__ WtBase)
{
    __shared__ unsigned short T[64][72];
    const int z = blockIdx.z;
    const int t = threadIdx.x;

    if (blockIdx.x < 4096) {
        const float* X = z==0 ? X0 : (z==1 ? X1 : X2);
        unsigned short* O = z==0 ? O0 : (z==1 ? O1 : O2);
        int idx = blockIdx.x*256 + t;
        float4 xv = *(const float4*)&X[(size_t)idx*4];
        uint2 o;
        o.x = (unsigned)f2bf(xv.x) | ((unsigned)f2bf(xv.y) << 16);
        o.y = (unsigned)f2bf(xv.z) | ((unsigned)f2bf(xv.w) << 16);
        *(uint2*)&O[(size_t)idx*4] = o;
        return;
    }

    const float* W = z==0 ? Wq : (z==1 ? Wk : Wv);
    unsigned short* Out = WtBase + ((size_t)z << 20);
    const int bx2 = blockIdx.x - 4096;
    const int n0 = (bx2 & 15)*64, k0 = (bx2 >> 4)*64;
    const int tk = t >> 4, tn4 = (t & 15)*4;

    #pragma unroll
    for (int i=0;i<4;i++){
        int kk = tk + i*16;
        float4 wv = *(const float4*)&W[(size_t)(k0+kk)*D_ + n0 + tn4];
        T[tn4+0][kk] = f2bf(wv.x);
        T[tn4+1][kk] = f2bf(wv.y);
        T[tn4+2][kk] = f2bf(wv.z);
        T[tn4+3][kk] = f2bf(wv.w);
    }
    __syncthreads();

    const int n = t >> 2, seg = t & 3;
    uint4 a = *(uint4*)&T[n][seg*16];
    uint4 b = *(uint4*)&T[n][seg*16 + 8];
    *(uint4*)&Out[(size_t)(n0+n)*D_ + k0 + seg*16]     = a;
    *(uint4*)&Out[(size_t)(n0+n)*D_ + k0 + seg*16 + 8] = b;
}

// ---------------------------------------------------------------------------
// Projection GEMM, pure-DMA staging, XOR-swizzled LDS. Grid (8,32,3).
// which==0: output scaled by log2e/32.  which==2: output transposed.
// ---------------------------------------------------------------------------
__global__ __launch_bounds__(256) void proj_gemm(
    const unsigned short* __restrict__ A0, const unsigned short* __restrict__ A1,
    const unsigned short* __restrict__ A2, const unsigned short* __restrict__ WtBase,
    const float* __restrict__ b0, const float* __restrict__ b1,
    const float* __restrict__ b2, unsigned short* __restrict__ OutBase)
{
    const int which = blockIdx.z;
    const unsigned short* A  = which==0 ? A0 : (which==1 ? A1 : A2);
    const unsigned short* Bm = WtBase + ((size_t)which << 20);
    const float* bias        = which==0 ? b0 : (which==1 ? b1 : b2);
    unsigned short* Out      = OutBase + ((size_t)which << 22);
    const float oscale = (which==0) ? 0.04508422f : 1.0f;   // log2e/32

    __shared__ __align__(16) unsigned short As[128*64];
    __shared__ __align__(16) unsigned short Bs[128*64];

    const int t    = threadIdx.x;
    const int m0   = blockIdx.y * 128;
    const int n0   = blockIdx.x * 128;
    const int w    = t >> 6;
    const int lane = t & 63;
    const int l15  = lane & 15;
    const int quad = lane >> 4;
    const int wm   = w >> 1, wn = w & 1;

    f32x4 acc[4][4];
    #pragma unroll
    for (int i=0;i<4;i++)
        #pragma unroll
        for (int j=0;j<4;j++) acc[i][j] = (f32x4){0.f,0.f,0.f,0.f};

    float biasv[4];
    #pragma unroll
    for (int nt=0; nt<4; nt++)
        biasv[nt] = bias[n0 + wn*64 + nt*16 + l15];

    int sArow[4], sAkc[4];
    #pragma unroll
    for (int i=0;i<4;i++){
        int s  = (w*4 + i)*64 + lane;
        int r  = s >> 3, cs = s & 7;
        sArow[i] = r;
        sAkc[i]  = ((cs ^ (r & 7)) * 8);
    }

    for (int ks = 0; ks < 16; ++ks) {
        const int kb = ks * 64;
        #pragma unroll
        for (int i=0;i<4;i++){
            int s = (w*4 + i)*64 + lane;
            gload_lds16(A  + (size_t)(m0 + sArow[i])*D_ + kb + sAkc[i], (unsigned short*)As + s*8);
            gload_lds16(Bm + (size_t)(n0 + sArow[i])*D_ + kb + sAkc[i], (unsigned short*)Bs + s*8);
        }
        __syncthreads();

        #pragma unroll
        for (int kh=0; kh<2; kh++){
            short8 aF[4], bF[4];
            #pragma unroll
            for (int mt=0; mt<4; mt++){
                int r  = wm*64 + mt*16 + l15;
                int cs = (kh*4 + quad) ^ (r & 7);
                aF[mt] = *(const short8*)(As + r*64 + cs*8);
            }
            #pragma unroll
            for (int nt=0; nt<4; nt++){
                int r  = wn*64 + nt*16 + l15;
                int cs = (kh*4 + quad) ^ (r & 7);
                bF[nt] = *(const short8*)(Bs + r*64 + cs*8);
            }
            #pragma unroll
            for (int mt=0; mt<4; mt++)
                #pragma unroll
                for (int nt=0; nt<4; nt++)
                    acc[mt][nt] = MFMA16(aF[mt], bF[nt], acc[mt][nt]);
        }
        __syncthreads();
    }

    if (which != 2) {
        #pragma unroll
        for (int nt=0; nt<4; nt++){
            int n  = n0 + wn*64 + nt*16 + l15;
            int hh = n >> 6, dh = n & 63;
            #pragma unroll
            for (int mt=0; mt<4; mt++){
                #pragma unroll
                for (int r=0; r<4; r++){
                    int m  = m0 + wm*64 + mt*16 + quad*4 + r;
                    int bb = m >> 11, ss = m & (S_-1);
                    float v = (acc[mt][nt][r] + biasv[nt]) * oscale;
                    Out[((size_t)((bb*H_ + hh)*S_ + ss))*DH_ + dh] = f2bf(v);
                }
            }
        }
    } else {
        #pragma unroll
        for (int nt=0; nt<4; nt++){
            int n  = n0 + wn*64 + nt*16 + l15;
            int hh = n >> 6, dh = n & 63;
            #pragma unroll
            for (int mt=0; mt<4; mt++){
                int m  = m0 + wm*64 + mt*16 + quad*4;
                int bb = m >> 11, ss = m & (S_-1);
                uint2 pk;
                pk.x = packp(acc[mt][nt][0] + biasv[nt], acc[mt][nt][1] + biasv[nt]);
                pk.y = packp(acc[mt][nt][2] + biasv[nt], acc[mt][nt][3] + biasv[nt]);
                *(uint2*)&Out[((size_t)((bb*H_ + hh)*DH_ + dh))*S_ + ss] = pk;
            }
        }
    }
}

// ---------------------------------------------------------------------------
// Flash attention, fixed-max exp2 softmax, in-register P.
// Block = 128 q of one (b,h); 4 waves x 32 q (qs=2). Grid (16,16,2) = 512
// blocks = 2/CU. 128-key iterations: DMA dbuf of [128][64] K and V tiles,
// computed as 2x 64-key sub-tiles, ONE barrier per 128 keys (16 total).
// Static mask-bias table in LDS, folded into QK MFMA accumulator init.
// XCD-swizzled: each XCD serves 4 heads (2 MB K/V < 4 MB L2).
//
// Key-row permutation (per 64-key sub-tile): LDS K row l holds global key
//   g(l) = 32*(st&1) + 8*quad + 4*(st>>1) + r   (l = st*16+quad*4+r)
// so QK^T output sc[st][r] (lane quad) is the score of key 32(st&1)+8q+4(st>>1)+r,
// and {st0,st2} / {st1,st3} pack directly into pf0/pf1 (PV B-frag, k=quad*8+j).
// V^T is stored by TRUE key, matching the B-frag k index.
// ---------------------------------------------------------------------------
__global__ __launch_bounds__(256, 2) void attn_kernel(
    const unsigned short* __restrict__ ws, const int* __restrict__ mask,
    float* __restrict__ out)
{
    const unsigned short* Qh = ws;                      // [B][H][S][64], exp2-scaled
    const unsigned short* Kh = ws + (size_t)M_*D_;      // [B][H][S][64]
    const unsigned short* Vg = ws + 2*(size_t)M_*D_;    // [B][H][64][S]

    // XCD swizzle: XCD x gets 64 consecutive Wn values = all 16 q-tiles of
    // 4 heads -> 2 MB K/V working set per XCD L2.
    const int lin = blockIdx.x + (blockIdx.y << 4) + (blockIdx.z << 8);
    const int Wn  = (lin & 7)*64 + (lin >> 3);
    const int qt = Wn & 15;
    const int h  = (Wn >> 4) & 15;
    const int bb = Wn >> 8;

    const size_t base = ((size_t)(bb*H_ + h)) * S_ * DH_;
    const int q0 = qt * 128;

    __shared__ __align__(16) unsigned char smem[73728];
    unsigned short* KsB = (unsigned short*)smem;            // [2][128][64] key-permuted
    unsigned short* VtB = (unsigned short*)(smem + 32768);  // [2][128][64] true-key order
    float*          MsT = (float*)(smem + 65536);           // [2048] static mask bias
    float*          Ob  = (float*)smem;                     // [128][68] alias (epilogue)

    const int t    = threadIdx.x;
    const int w    = t >> 6;
    const int lane = t & 63;
    const int l15  = lane & 15;
    const int quad = lane >> 4;

    short8 qf[2][2];
    #pragma unroll
    for (int qs=0; qs<2; qs++){
        const unsigned short* qp = Qh + base + (size_t)(q0 + w*32 + qs*16 + l15)*DH_ + quad*8;
        qf[qs][0] = *(const short8*)(qp);
        qf[qs][1] = *(const short8*)(qp + 32);
    }

    f32x4 accO[2][4];
    #pragma unroll
    for (int qs=0; qs<2; qs++)
        #pragma unroll
        for (int i=0;i<4;i++) accO[qs][i] = (f32x4){0.f,0.f,0.f,0.f};
    f32x4 lv[2] = {(f32x4){0.f,0.f,0.f,0.f}, (f32x4){0.f,0.f,0.f,0.f}};

    // staging slots: 1024 slots of 16B per buffer; K source row permuted.
    // slot row r in 0..127: sub-tile = r>>6, within-sub row = r&63.
    int rr[4], cc[4], ssl[4], gK[4];
    #pragma unroll
    for (int i=0;i<4;i++){
        int s  = (w*4 + i)*64 + lane;   // 0..1023
        int r  = s >> 3, cs = s & 7;
        int r6 = r & 63;
        ssl[i] = s;
        rr[i]  = r;
        cc[i]  = (cs ^ (r & 7)) * 8;
        gK[i]  = (r & 64) + ((r6 >> 4) & 1)*32 + ((r6 >> 2) & 3)*8 + (r6 >> 5)*4 + (r6 & 3);
    }

    #define ISSUE128(k0v, p) do {                                              \
        _Pragma("unroll")                                                      \
        for (int i=0;i<4;i++){                                                 \
            gload_lds16(Kh + base + (size_t)((k0v) + gK[i])*DH_ + cc[i],       \
                        KsB + (p)*8192 + ssl[i]*8);                            \
            gload_lds16(Vg + base + (size_t)(rr[i] & 63)*S_ + (k0v)            \
                            + (rr[i] & 64) + cc[i],                            \
                        VtB + (p)*8192 + ssl[i]*8);                            \
        }                                                                      \
    } while(0)

    // prologue: static mask-bias table + first DMA tile
    ISSUE128(0, 0);
    #pragma unroll
    for (int i=0;i<8;i++){
        int idx = i*256 + t;
        MsT[idx] = mask[bb*S_ + idx] ? 0.f : -1e9f;
    }
    __syncthreads();

    for (int it = 0; it < 16; ++it){
        const int p = it & 1;
        if (it < 15) ISSUE128((it+1)*128, 1-p);

        #pragma unroll
        for (int sb = 0; sb < 2; ++sb){
            const unsigned short* Ks  = KsB + p*8192 + sb*4096;
            const unsigned short* Vts = VtB + p*8192 + sb*4096;
            const float*          Mp  = MsT + it*128 + sb*64;

            // mask bias in permuted-key order (MFMA C-init):
            // key(st,quad,r) = 32(st&1)+4(st>>1)+8quad+r
            f32x4 msv[4];
            #pragma unroll
            for (int st=0; st<4; st++)
                msv[st] = *(const f32x4*)&Mp[(st&1)*32 + (st>>1)*4 + quad*8];

            // K/V fragments: loaded ONCE per sub-tile, shared by both qs
            short8 ka[4], kb[4];
            #pragma unroll
            for (int st=0; st<4; st++){
                int row = st*16 + l15;
                const unsigned short* kr = Ks + row*64;
                ka[st] = *(const short8*)(kr + ((quad    ) ^ (row & 7))*8);
                kb[st] = *(const short8*)(kr + ((quad + 4) ^ (row & 7))*8);
            }
            short8 vf[4][2];
            #pragma unroll
            for (int mt=0; mt<4; mt++){
                int row = mt*16 + l15;
                const unsigned short* vr = Vts + row*64;
                vf[mt][0] = *(const short8*)(vr + ((quad    ) ^ (row & 7))*8);
                vf[mt][1] = *(const short8*)(vr + ((quad + 4) ^ (row & 7))*8);
            }

            #pragma unroll
            for (int qs=0; qs<2; qs++){
                // ---- scores: S^T = K·Q^T, mask bias as accumulator init ----
                f32x4 sc[4];
                __builtin_amdgcn_s_setprio(1);
                #pragma unroll
                for (int st=0; st<4; st++){
                    f32x4 a = msv[st];
                    a = MFMA16(ka[st], qf[qs][0], a);
                    a = MFMA16(kb[st], qf[qs][1], a);
                    sc[st] = a;
                }
                __builtin_amdgcn_s_setprio(0);
                // ---- fixed-max softmax, tree-summed l, packed into B-frag ----
                f32x4 pvv[4];
                #pragma unroll
                for (int st=0; st<4; st++)
                    #pragma unroll
                    for (int rj=0; rj<4; rj++)
                        pvv[st][rj] = __builtin_amdgcn_exp2f(sc[st][rj]);
                f32x4 s01 = pvv[0] + pvv[1];
                f32x4 s23 = pvv[2] + pvv[3];
                lv[qs] += (s01 + s23);
                u32x4 u0 = { packp(pvv[0][0],pvv[0][1]), packp(pvv[0][2],pvv[0][3]),
                             packp(pvv[2][0],pvv[2][1]), packp(pvv[2][2],pvv[2][3]) };
                u32x4 u1 = { packp(pvv[1][0],pvv[1][1]), packp(pvv[1][2],pvv[1][3]),
                             packp(pvv[3][0],pvv[3][1]), packp(pvv[3][2],pvv[3][3]) };
                short8 pf0 = __builtin_bit_cast(short8, u0);
                short8 pf1 = __builtin_bit_cast(short8, u1);
                // ---- PV: O^T += V^T · P^T (P entirely in registers) ----
                __builtin_amdgcn_s_setprio(1);
                #pragma unroll
                for (int mt=0; mt<4; mt++){
                    accO[qs][mt] = MFMA16(vf[mt][0], pf0, accO[qs][mt]);
                    accO[qs][mt] = MFMA16(vf[mt][1], pf1, accO[qs][mt]);
                }
                __builtin_amdgcn_s_setprio(0);
            }
        }
        __syncthreads();
    }

    // ---- epilogue: reduce l across quads ONCE, normalize, transpose, store ----
    #pragma unroll
    for (int qs=0; qs<2; qs++){
        float l = (lv[qs][0] + lv[qs][1]) + (lv[qs][2] + lv[qs][3]);
        l += __shfl_xor(l, 16);
        l += __shfl_xor(l, 32);
        float invl = 1.0f / fmaxf(l, 1e-30f);
        #pragma unroll
        for (int mt=0; mt<4; mt++)
            #pragma unroll
            for (int r=0; r<4; r++)
                Ob[(w*32 + qs*16 + l15)*68 + mt*16 + quad*4 + r] = accO[qs][mt][r]*invl;
    }
    __syncthreads();

    #pragma unroll
    for (int i=0;i<8;i++){
        int f  = (i*256 + t)*4;
        int qq = f >> 6, dh = f & 63;
        float4 o = *(float4*)&Ob[qq*68 + dh];
        *(float4*)&out[((size_t)(bb*S_ + q0 + qq))*D_ + h*DH_ + dh] = o;
    }
    #undef ISSUE128
}

extern "C" void kernel_launch(void* const* d_in, const int* in_sizes, int n_in,
                              void* d_out, int out_size, void* d_ws, size_t ws_size,
                              hipStream_t stream) {
    const float* q    = (const float*)d_in[0];
    const float* k    = (const float*)d_in[1];
    const float* v    = (const float*)d_in[2];
    const int*   mask = (const int*)d_in[3];
    const float* Wq   = (const float*)d_in[4];
    const float* b0   = (const float*)d_in[5];
    const float* Wk   = (const float*)d_in[6];
    const float* b1   = (const float*)d_in[7];
    const float* Wv   = (const float*)d_in[8];
    const float* b2   = (const float*)d_in[9];
    float* out = (float*)d_out;
    unsigned short* ws = (unsigned short*)d_ws;   // 39.85 MB used

    // Xb slots: q -> ws; k,v -> d_out (scratch until attn overwrites it last)
    unsigned short* xq = ws + XB_OFF;
    unsigned short* xk = (unsigned short*)d_out;
    unsigned short* xv = (unsigned short*)d_out + 4194304;

    convert_all<<<dim3(4352,1,3), 256, 0, stream>>>(q, k, v, Wq, Wk, Wv,
                                                    xq, xk, xv, ws + WT_OFF);
    proj_gemm<<<dim3(8,32,3), 256, 0, stream>>>(xq, xk, xv, ws + WT_OFF,
                                                b0, b1, b2, ws);
    attn_kernel<<<dim3(16,16,2), 256, 0, stream>>>(ws, mask, out);
}